// Round 1
// baseline (124.966 us; speedup 1.0000x reference)
//
#include <hip/hip_runtime.h>
#include <hip/hip_bf16.h>
#include <cstdint>
#include <cstddef>

typedef __attribute__((ext_vector_type(8))) short bf16x8;
typedef __attribute__((ext_vector_type(4))) float f32x4;
typedef unsigned short u16;
typedef unsigned int u32;

#define DEV static __device__ __forceinline__

constexpr int Bc = 2, Sc = 1024, DMc = 1024, Hc = 16, DKc = 64;

DEV u16 f2bf(float f) {
  u32 u = __float_as_uint(f);
  u32 r = (u + 0x7FFFu + ((u >> 16) & 1u)) >> 16;
  return (u16)r;
}
DEV float bf2f(u16 h) { return __uint_as_float(((u32)h) << 16); }

// ---------------- f32 -> bf16 conversion ----------------
struct CvtJob { const float* in; u16* out; int n; };
struct CvtArgs { CvtJob j[8]; };

__global__ __launch_bounds__(256) void cvt_kernel(CvtArgs a) {
  CvtJob job = a.j[blockIdx.y];
  int i = (int)(blockIdx.x * 256 + threadIdx.x) * 4;
  if (i >= job.n) return;
  float4 v = *(const float4*)(job.in + i);
  ushort4 o;
  o.x = f2bf(v.x); o.y = f2bf(v.y); o.z = f2bf(v.z); o.w = f2bf(v.w);
  *(ushort4*)(job.out + i) = o;
}

// ---------------- GEMM: C = A(MxK) * W(NxK)^T + bias ----------------
// MODE 0: write bf16 head-split [b,h,s,d] (m=b*S+s, n=h*64+d)
// MODE 1: write f32 row-major [m][n]
struct GemmJob { const u16* A; const u16* W; const float* bias; void* out; };
struct GemmJobs { GemmJob p[3]; };

template<int MODE>
__global__ __launch_bounds__(256) void gemm_bt(GemmJobs G, int K) {
  GemmJob P = G.p[blockIdx.z];
  __shared__ __align__(16) u16 sA[128 * 64];
  __shared__ __align__(16) u16 sB[128 * 64];
  const int tid = threadIdx.x, lane = tid & 63, w = tid >> 6;
  const int cl = lane & 15, rg = lane >> 4;
  const int m0 = blockIdx.y * 128, n0 = blockIdx.x * 128;
  const int wm = (w >> 1) * 64, wn = (w & 1) * 64;
  f32x4 acc[4][4] = {};

  for (int k0 = 0; k0 < K; k0 += 64) {
    __syncthreads();
    #pragma unroll
    for (int i = 0; i < 4; ++i) {
      int fc = i * 256 + tid;
      int row = fc >> 3, c = fc & 7;
      float4 x = *(const float4*)(P.A + (size_t)(m0 + row) * K + k0 + c * 8);
      float4 y = *(const float4*)(P.W + (size_t)(n0 + row) * K + k0 + c * 8);
      *(float4*)((char*)sA + (row * 8 + (c ^ (row & 7))) * 16) = x;
      *(float4*)((char*)sB + (row * 8 + (c ^ (row & 7))) * 16) = y;
    }
    __syncthreads();
    #pragma unroll
    for (int kk = 0; kk < 2; ++kk) {
      bf16x8 af[4], bfr[4];
      #pragma unroll
      for (int mi = 0; mi < 4; ++mi) {
        int row = wm + mi * 16 + cl;
        af[mi] = *(const bf16x8*)((char*)sA + (row * 8 + ((kk * 4 + rg) ^ (row & 7))) * 16);
      }
      #pragma unroll
      for (int ni = 0; ni < 4; ++ni) {
        int row = wn + ni * 16 + cl;
        bfr[ni] = *(const bf16x8*)((char*)sB + (row * 8 + ((kk * 4 + rg) ^ (row & 7))) * 16);
      }
      #pragma unroll
      for (int mi = 0; mi < 4; ++mi)
        #pragma unroll
        for (int ni = 0; ni < 4; ++ni)
          acc[mi][ni] = __builtin_amdgcn_mfma_f32_16x16x32_bf16(af[mi], bfr[ni], acc[mi][ni], 0, 0, 0);
    }
  }
  #pragma unroll
  for (int mi = 0; mi < 4; ++mi) {
    #pragma unroll
    for (int ni = 0; ni < 4; ++ni) {
      #pragma unroll
      for (int j = 0; j < 4; ++j) {
        int m = m0 + wm + mi * 16 + rg * 4 + j;
        int n = n0 + wn + ni * 16 + cl;
        float v = acc[mi][ni][j] + P.bias[n];
        if (MODE == 0) {
          int b = m >> 10, s = m & 1023, h = n >> 6, d = n & 63;
          ((u16*)P.out)[((size_t)(b * Hc + h) * Sc + s) * DKc + d] = f2bf(v);
        } else {
          ((float*)P.out)[(size_t)m * DMc + n] = v;
        }
      }
    }
  }
}

// ---------------- V [bh][s][64] -> V^T [bh][64][S] ----------------
__global__ __launch_bounds__(256) void transpose_v(const u16* __restrict__ v, u16* __restrict__ vt) {
  __shared__ __align__(16) u16 t[64][72];
  int bh = blockIdx.y, s0 = blockIdx.x * 64;
  int tid = threadIdx.x;
  int sr = tid >> 2, c4 = tid & 3;
  const u16* src = v + ((size_t)bh * Sc + s0 + sr) * DKc + c4 * 16;
  float4 x0 = *(const float4*)src;
  float4 x1 = *(const float4*)(src + 8);
  const u16* e0 = (const u16*)&x0;
  const u16* e1 = (const u16*)&x1;
  #pragma unroll
  for (int e = 0; e < 8; ++e) t[c4 * 16 + e][sr] = e0[e];
  #pragma unroll
  for (int e = 0; e < 8; ++e) t[c4 * 16 + 8 + e][sr] = e1[e];
  __syncthreads();
  int dr = tid >> 2, sc = (tid & 3) * 16;
  u16* dst = vt + ((size_t)bh * DKc + dr) * Sc + s0 + sc;
  float4 r0 = *(const float4*)&t[dr][sc];
  float4 r1 = *(const float4*)&t[dr][sc + 8];
  *(float4*)dst = r0;
  *(float4*)(dst + 8) = r1;
}

// ---------------- fused relative attention ----------------
// grid: (S/64, B*H); block 256 (4 waves x 16 q-rows)
__global__ __launch_bounds__(256) void attn_rel(
    const u16* __restrict__ qg, const u16* __restrict__ kg,
    const u16* __restrict__ vtg, const u16* __restrict__ erg,
    u16* __restrict__ og) {
  __shared__ __align__(16) u16 sK[64 * 64];    // swizzled [s][d]
  __shared__ __align__(16) u16 sV[64 * 64];    // swizzled V^T [d][s]
  __shared__ __align__(16) u16 sE[128 * 64];   // swizzled [r][d]
  __shared__ u16 sT[4][16 * 132];              // per-wave T (bf16)
  __shared__ __align__(16) u16 sP[4][16 * 72]; // per-wave P (bf16)

  const int tid = threadIdx.x, lane = tid & 63, w = tid >> 6;
  const int cl = lane & 15, rg = lane >> 4;
  const int bh = blockIdx.y;
  const int q0 = blockIdx.x * 64;

  bf16x8 qf0, qf1;
  {
    const u16* qp = qg + ((size_t)bh * Sc + q0 + w * 16 + cl) * DKc + rg * 8;
    qf0 = *(const bf16x8*)qp;
    qf1 = *(const bf16x8*)(qp + 32);
  }
  f32x4 oacc[4] = {};
  float mrow[4] = {-1e30f, -1e30f, -1e30f, -1e30f};
  float lrow[4] = {0.f, 0.f, 0.f, 0.f};
  u16* Tw = sT[w];
  u16* Pw = sP[w];

  for (int t = 0; t < 16; ++t) {
    const int k0 = t * 64;
    __syncthreads();
    #pragma unroll
    for (int i = 0; i < 2; ++i) {
      int fc = i * 256 + tid, row = fc >> 3, c = fc & 7;
      float4 x = *(const float4*)(kg + ((size_t)bh * Sc + k0 + row) * DKc + c * 8);
      *(float4*)((char*)sK + (row * 8 + (c ^ (row & 7))) * 16) = x;
      float4 y = *(const float4*)(vtg + ((size_t)bh * DKc + row) * Sc + k0 + c * 8);
      *(float4*)((char*)sV + (row * 8 + (c ^ (row & 7))) * 16) = y;
    }
    const int r0 = q0 - k0 + 960;  // window base into Er (always in [0,1920])
    #pragma unroll
    for (int i = 0; i < 4; ++i) {
      int fc = i * 256 + tid, row = fc >> 3, c = fc & 7;
      float4 x = *(const float4*)(erg + (size_t)(r0 + row) * DKc + c * 8);
      *(float4*)((char*)sE + (row * 8 + (c ^ (row & 7))) * 16) = x;
    }
    __syncthreads();

    // QK^T: 16x64 scores per wave
    f32x4 sc4[4];
    #pragma unroll
    for (int nc = 0; nc < 4; ++nc) {
      int row = nc * 16 + cl;
      bf16x8 b0 = *(const bf16x8*)((char*)sK + (row * 8 + ((rg)     ^ (row & 7))) * 16);
      bf16x8 b1 = *(const bf16x8*)((char*)sK + (row * 8 + ((rg + 4) ^ (row & 7))) * 16);
      f32x4 a = {};
      a = __builtin_amdgcn_mfma_f32_16x16x32_bf16(qf0, b0, a, 0, 0, 0);
      a = __builtin_amdgcn_mfma_f32_16x16x32_bf16(qf1, b1, a, 0, 0, 0);
      sc4[nc] = a;
    }
    // T = Q . Er_window^T, only the 5 column-chunks this wave needs
    #pragma unroll
    for (int rc0 = 0; rc0 < 5; ++rc0) {
      int rc = w + rc0;
      int row = rc * 16 + cl;
      bf16x8 b0 = *(const bf16x8*)((char*)sE + (row * 8 + ((rg)     ^ (row & 7))) * 16);
      bf16x8 b1 = *(const bf16x8*)((char*)sE + (row * 8 + ((rg + 4) ^ (row & 7))) * 16);
      f32x4 a = {};
      a = __builtin_amdgcn_mfma_f32_16x16x32_bf16(qf0, b0, a, 0, 0, 0);
      a = __builtin_amdgcn_mfma_f32_16x16x32_bf16(qf1, b1, a, 0, 0, 0);
      #pragma unroll
      for (int j = 0; j < 4; ++j)
        Tw[(rg * 4 + j) * 132 + rc * 16 + cl] = f2bf(a[j]);
    }
    // gather relative term + online softmax
    #pragma unroll
    for (int j = 0; j < 4; ++j) {
      const int qi = rg * 4 + j;
      float sv[4];
      float mx = -1e30f;
      #pragma unroll
      for (int nc = 0; nc < 4; ++nc) {
        int r = qi + w * 16 + 63 - (nc * 16 + cl);  // in [w*16, w*16+78]
        float tval = bf2f(Tw[qi * 132 + r]);
        float s = (sc4[nc][j] + tval) * 0.125f;
        sv[nc] = s;
        mx = fmaxf(mx, s);
      }
      #pragma unroll
      for (int off = 1; off < 16; off <<= 1)
        mx = fmaxf(mx, __shfl_xor(mx, off));
      float mnew = fmaxf(mrow[j], mx);
      float alpha = __expf(mrow[j] - mnew);
      mrow[j] = mnew;
      float rs = 0.f;
      #pragma unroll
      for (int nc = 0; nc < 4; ++nc) {
        float pv = __expf(sv[nc] - mnew);
        rs += pv;
        Pw[qi * 72 + nc * 16 + cl] = f2bf(pv);
      }
      #pragma unroll
      for (int off = 1; off < 16; off <<= 1)
        rs += __shfl_xor(rs, off);
      lrow[j] = lrow[j] * alpha + rs;
      #pragma unroll
      for (int dc = 0; dc < 4; ++dc) oacc[dc][j] *= alpha;
    }
    // PV
    bf16x8 pa0 = *(const bf16x8*)((const char*)Pw + (cl * 72 + rg * 8) * 2);
    bf16x8 pa1 = *(const bf16x8*)((const char*)Pw + (cl * 72 + 32 + rg * 8) * 2);
    #pragma unroll
    for (int dc = 0; dc < 4; ++dc) {
      int row = dc * 16 + cl;
      bf16x8 b0 = *(const bf16x8*)((char*)sV + (row * 8 + ((rg)     ^ (row & 7))) * 16);
      bf16x8 b1 = *(const bf16x8*)((char*)sV + (row * 8 + ((rg + 4) ^ (row & 7))) * 16);
      oacc[dc] = __builtin_amdgcn_mfma_f32_16x16x32_bf16(pa0, b0, oacc[dc], 0, 0, 0);
      oacc[dc] = __builtin_amdgcn_mfma_f32_16x16x32_bf16(pa1, b1, oacc[dc], 0, 0, 0);
    }
  }
  // epilogue: O/l -> bf16 [m=(b,s)][n=(h,d)]
  const int b = bh >> 4, h = bh & 15;
  #pragma unroll
  for (int dc = 0; dc < 4; ++dc) {
    #pragma unroll
    for (int j = 0; j < 4; ++j) {
      int qrow = q0 + w * 16 + rg * 4 + j;
      float v = oacc[dc][j] / lrow[j];
      og[((size_t)(b * Sc + qrow)) * DMc + h * DKc + dc * 16 + cl] = f2bf(v);
    }
  }
}

// ---------------- host ----------------
extern "C" void kernel_launch(void* const* d_in, const int* in_sizes, int n_in,
                              void* d_out, int out_size, void* d_ws, size_t ws_size,
                              hipStream_t stream) {
  (void)in_sizes; (void)n_in; (void)out_size; (void)ws_size;
  const float* query = (const float*)d_in[0];
  const float* key_  = (const float*)d_in[1];
  const float* value = (const float*)d_in[2];
  const float* Wq = (const float*)d_in[3];
  const float* Wk = (const float*)d_in[4];
  const float* Wv = (const float*)d_in[5];
  const float* Wo = (const float*)d_in[6];
  const float* bq = (const float*)d_in[7];
  const float* bk = (const float*)d_in[8];
  const float* bv = (const float*)d_in[9];
  const float* bo = (const float*)d_in[10];
  const float* Er = (const float*)d_in[11];

  char* p = (char*)d_ws;
  size_t off = 0;
  auto alloc = [&](size_t bytes) {
    char* r = p + off;
    off += (bytes + 255) & ~(size_t)255;
    return r;
  };
  u16* Xq  = (u16*)alloc((size_t)2048 * 1024 * 2);
  u16* Xk  = (u16*)alloc((size_t)2048 * 1024 * 2);
  u16* Xv  = (u16*)alloc((size_t)2048 * 1024 * 2);
  u16* Wqb = (u16*)alloc((size_t)1024 * 1024 * 2);
  u16* Wkb = (u16*)alloc((size_t)1024 * 1024 * 2);
  u16* Wvb = (u16*)alloc((size_t)1024 * 1024 * 2);
  u16* Wob = (u16*)alloc((size_t)1024 * 1024 * 2);
  u16* Erb = (u16*)alloc((size_t)2048 * 64 * 2);   // 2047 rows used, 1 spare
  u16* qh  = (u16*)alloc((size_t)2048 * 1024 * 2); // [b,h,s,d]
  u16* kh  = (u16*)alloc((size_t)2048 * 1024 * 2);
  u16* vh  = (u16*)alloc((size_t)2048 * 1024 * 2);
  u16* vt  = (u16*)alloc((size_t)2048 * 1024 * 2); // [b,h,d,s]
  u16* attnb = (u16*)alloc((size_t)2048 * 1024 * 2);

  CvtArgs ca;
  ca.j[0] = {query, Xq, 2048 * 1024};
  ca.j[1] = {key_,  Xk, 2048 * 1024};
  ca.j[2] = {value, Xv, 2048 * 1024};
  ca.j[3] = {Wq, Wqb, 1024 * 1024};
  ca.j[4] = {Wk, Wkb, 1024 * 1024};
  ca.j[5] = {Wv, Wvb, 1024 * 1024};
  ca.j[6] = {Wo, Wob, 1024 * 1024};
  ca.j[7] = {Er, Erb, 2047 * 64};
  cvt_kernel<<<dim3(2048, 8, 1), 256, 0, stream>>>(ca);

  GemmJobs gp;
  gp.p[0] = {Xq, Wqb, bq, (void*)qh};
  gp.p[1] = {Xk, Wkb, bk, (void*)kh};
  gp.p[2] = {Xv, Wvb, bv, (void*)vh};
  gemm_bt<0><<<dim3(8, 16, 3), 256, 0, stream>>>(gp, 1024);

  transpose_v<<<dim3(16, 32, 1), 256, 0, stream>>>(vh, vt);

  attn_rel<<<dim3(16, 32, 1), 256, 0, stream>>>(qh, kh, vt, Erb, attnb);

  GemmJobs go;
  go.p[0] = {attnb, Wob, bo, d_out};
  go.p[1] = go.p[0];
  go.p[2] = go.p[0];
  gemm_bt<1><<<dim3(8, 16, 1), 256, 0, stream>>>(go, 1024);
}